// Round 3
// baseline (886.090 us; speedup 1.0000x reference)
//
#include <hip/hip_runtime.h>
#include <hip/hip_bf16.h>
#include <math.h>

#define N_ENVS   4096
#define N_AGENTS 64
#define OBS_DIM  256
#define HIDDEN   512
#define HEADK    32
#define BE       64   // envs per block

typedef __attribute__((ext_vector_type(8))) short bf16x8;
typedef __attribute__((ext_vector_type(8))) unsigned short u16x8;
typedef __attribute__((ext_vector_type(4))) float f32x4;

static __device__ __forceinline__ unsigned short f2bf(float x) {
    union { float f; unsigned int u; } v; v.f = x;
    unsigned int r = (v.u + 0x7FFFu + ((v.u >> 16) & 1u)) >> 16;
    return (unsigned short)r;
}

// Convert + transpose weights to bf16, N-major (so B-fragments are 16B contiguous).
__global__ void prep_weights_kernel(const float* __restrict__ W1,
                                    const float* __restrict__ W2,
                                    const float* __restrict__ HW1,
                                    unsigned short* __restrict__ W1T,
                                    unsigned short* __restrict__ W2T,
                                    unsigned short* __restrict__ HW1T) {
    int id = blockIdx.x * 256 + threadIdx.x;
    if (id < 131072) {                      // W1 [256][512] -> W1T [512][256]
        int k = id >> 9, n = id & 511;
        W1T[n * 256 + k] = f2bf(W1[id]);
    } else if (id < 131072 + 262144) {      // W2 [512][512] -> W2T [512][512]
        int t = id - 131072;
        int k = t >> 9, n = t & 511;
        W2T[n * 512 + k] = f2bf(W2[t]);
    } else if (id < 131072 + 262144 + 1048576) {  // HW1 [64][512][32] -> HW1T [64][32][512]
        int t = id - (131072 + 262144);
        int ag = t >> 14;
        int rem = t & 16383;
        int hh = rem >> 5, c = rem & 31;
        HW1T[((ag << 5) + c) * 512 + hh] = f2bf(HW1[t]);
    }
}

// Fused: obs -> (GEMM1 relu) -> (GEMM2 relu) -> per-agent head1 relu -> head2 sigmoid.
// Block = 64 envs x 1 agent. 512 threads = 8 waves (2 row x 4 col).
// ONE 64KB LDS buffer serves obs (32KB) -> h (64KB) -> feat (64KB): accumulators
// stay in regs across a barrier between last-read and overwrite. 73KB total ->
// 2 blocks/CU. K-loops use round-1 low-pressure form (inline B loads, unroll 2)
// to stay under the 128-VGPR cap WITHOUT spilling (round-2 lesson: bfr[8]
// clusters + full unroll -> 403MB scratch traffic).
__launch_bounds__(512, 4)
__global__ void fused_mlp_kernel(const float* __restrict__ obs,
                                 const float* __restrict__ b1,
                                 const float* __restrict__ b2,
                                 const float* __restrict__ Hb1,
                                 const float* __restrict__ HW2,
                                 const float* __restrict__ Hb2,
                                 const unsigned short* __restrict__ W1T,
                                 const unsigned short* __restrict__ W2T,
                                 const unsigned short* __restrict__ HW1T,
                                 float* __restrict__ out) {
    __shared__ unsigned short buf[BE * 512];    // 64 KB: obs tile, then h, then feat
    __shared__ float gpart[BE * 36];            // 9 KB : g partials (pad 36)

    const int tid  = threadIdx.x;
    const int lane = tid & 63;
    const int wid  = tid >> 6;
    const int wr   = wid >> 2;   // 0..1  (row half)
    const int wc   = wid & 3;    // 0..3  (col quarter)
    const int l15  = lane & 15;
    const int lk   = lane >> 4;  // 0..3
    const int e0   = blockIdx.x * BE;
    const int ag   = blockIdx.y;

    const f32x4 fzero = {0.f, 0.f, 0.f, 0.f};

    // ---------------- stage obs tile (fp32 -> bf16, swizzled, [64][256]) ----------------
    {
        const float* src = obs + (size_t)e0 * (N_AGENTS * OBS_DIM) + (size_t)ag * OBS_DIM;
        #pragma unroll
        for (int g = 0; g < 4; ++g) {
            int gi  = tid + 512 * g;            // 2048 groups of 8 elems
            int row = gi >> 5;                  // 32 groups per row
            int kg  = (gi & 31) << 3;
            const float4* p = reinterpret_cast<const float4*>(src + (size_t)row * (N_AGENTS * OBS_DIM) + kg);
            float4 v0 = p[0], v1 = p[1];
            u16x8 w;
            w[0] = f2bf(v0.x); w[1] = f2bf(v0.y); w[2] = f2bf(v0.z); w[3] = f2bf(v0.w);
            w[4] = f2bf(v1.x); w[5] = f2bf(v1.y); w[6] = f2bf(v1.z); w[7] = f2bf(v1.w);
            int byt = (row * 512 + kg * 2) ^ ((row & 7) << 4);
            *reinterpret_cast<u16x8*>(&buf[byt >> 1]) = w;
        }
    }
    __syncthreads();

    // ---------------- GEMM1: h = relu(obs @ W1 + b1), K=256 ----------------
    f32x4 acc[2][8];
    #pragma unroll
    for (int i = 0; i < 2; ++i)
        #pragma unroll
        for (int j = 0; j < 8; ++j) acc[i][j] = fzero;

    #pragma unroll 2
    for (int ks = 0; ks < 8; ++ks) {
        const int kk = ks * 32 + lk * 8;
        bf16x8 af[2];
        #pragma unroll
        for (int mi = 0; mi < 2; ++mi) {
            int row = wr * 32 + mi * 16 + l15;
            int byt = (row * 512 + kk * 2) ^ ((row & 7) << 4);
            af[mi] = *reinterpret_cast<const bf16x8*>(&buf[byt >> 1]);
        }
        #pragma unroll
        for (int ni = 0; ni < 8; ++ni) {
            int col = wc * 128 + ni * 16 + l15;
            bf16x8 bf = *reinterpret_cast<const bf16x8*>(&W1T[col * 256 + kk]);
            acc[0][ni] = __builtin_amdgcn_mfma_f32_16x16x32_bf16(af[0], bf, acc[0][ni], 0, 0, 0);
            acc[1][ni] = __builtin_amdgcn_mfma_f32_16x16x32_bf16(af[1], bf, acc[1][ni], 0, 0, 0);
        }
    }
    __syncthreads();   // all obs reads done -> safe to overwrite buf with h

    // epilogue: +b1, relu, write h into buf ([64][512] swizzled)
    #pragma unroll
    for (int mi = 0; mi < 2; ++mi)
        #pragma unroll
        for (int ni = 0; ni < 8; ++ni) {
            int col = wc * 128 + ni * 16 + l15;
            float bias = b1[col];
            #pragma unroll
            for (int r = 0; r < 4; ++r) {
                int row = wr * 32 + mi * 16 + lk * 4 + r;
                float v = acc[mi][ni][r] + bias;
                v = v > 0.f ? v : 0.f;
                int byt = (row * 1024 + col * 2) ^ ((row & 7) << 4);
                buf[byt >> 1] = f2bf(v);
            }
        }
    __syncthreads();

    // ---------------- GEMM2: feat = relu(h @ W2 + b2), K=512 ----------------
    #pragma unroll
    for (int i = 0; i < 2; ++i)
        #pragma unroll
        for (int j = 0; j < 8; ++j) acc[i][j] = fzero;

    #pragma unroll 2
    for (int ks = 0; ks < 16; ++ks) {
        const int kk = ks * 32 + lk * 8;
        bf16x8 af[2];
        #pragma unroll
        for (int mi = 0; mi < 2; ++mi) {
            int row = wr * 32 + mi * 16 + l15;
            int byt = (row * 1024 + kk * 2) ^ ((row & 7) << 4);
            af[mi] = *reinterpret_cast<const bf16x8*>(&buf[byt >> 1]);
        }
        #pragma unroll
        for (int ni = 0; ni < 8; ++ni) {
            int col = wc * 128 + ni * 16 + l15;
            bf16x8 bf = *reinterpret_cast<const bf16x8*>(&W2T[col * 512 + kk]);
            acc[0][ni] = __builtin_amdgcn_mfma_f32_16x16x32_bf16(af[0], bf, acc[0][ni], 0, 0, 0);
            acc[1][ni] = __builtin_amdgcn_mfma_f32_16x16x32_bf16(af[1], bf, acc[1][ni], 0, 0, 0);
        }
    }
    __syncthreads();   // all h reads done -> safe to overwrite buf with feat

    // epilogue: +b2, relu, write feat into buf ([64][512] swizzled)
    #pragma unroll
    for (int mi = 0; mi < 2; ++mi)
        #pragma unroll
        for (int ni = 0; ni < 8; ++ni) {
            int col = wc * 128 + ni * 16 + l15;
            float bias = b2[col];
            #pragma unroll
            for (int r = 0; r < 4; ++r) {
                int row = wr * 32 + mi * 16 + lk * 4 + r;
                float v = acc[mi][ni][r] + bias;
                v = v > 0.f ? v : 0.f;
                int byt = (row * 1024 + col * 2) ^ ((row & 7) << 4);
                buf[byt >> 1] = f2bf(v);
            }
        }
    __syncthreads();

    // ---------------- head1: g = relu(feat @ HW1[ag] + Hb1[ag]), N=32 ----------------
    // All 8 waves: 4-way M (16 rows each) x 2-way K-split (256 each), LDS reduce.
    {
        const int hm = wid >> 1;    // 0..3
        const int hk = wid & 1;     // 0..1
        f32x4 hacc[2] = {fzero, fzero};
        const unsigned short* hbase = HW1T + (size_t)((ag << 5) + l15) * 512 + hk * 256;
        #pragma unroll 2
        for (int ks = 0; ks < 8; ++ks) {
            const int kk = hk * 256 + ks * 32 + lk * 8;
            int row = hm * 16 + l15;
            int byt = (row * 1024 + kk * 2) ^ ((row & 7) << 4);
            bf16x8 afh = *reinterpret_cast<const bf16x8*>(&buf[byt >> 1]);
            #pragma unroll
            for (int ni = 0; ni < 2; ++ni) {
                bf16x8 bfh = *reinterpret_cast<const bf16x8*>(hbase + ni * 16 * 512 + ks * 32 + lk * 8);
                hacc[ni] = __builtin_amdgcn_mfma_f32_16x16x32_bf16(afh, bfh, hacc[ni], 0, 0, 0);
            }
        }
        if (hk == 0) {
            #pragma unroll
            for (int ni = 0; ni < 2; ++ni) {
                int col = ni * 16 + l15;
                float hb = Hb1[(ag << 5) + col];
                #pragma unroll
                for (int r = 0; r < 4; ++r) {
                    int row = hm * 16 + lk * 4 + r;
                    gpart[row * 36 + col] = hacc[ni][r] + hb;
                }
            }
        }
        __syncthreads();
        if (hk == 1) {
            #pragma unroll
            for (int ni = 0; ni < 2; ++ni) {
                int col = ni * 16 + l15;
                #pragma unroll
                for (int r = 0; r < 4; ++r) {
                    int row = hm * 16 + lk * 4 + r;
                    float v = gpart[row * 36 + col] + hacc[ni][r];
                    gpart[row * 36 + col] = v > 0.f ? v : 0.f;
                }
            }
        }
        __syncthreads();
    }

    // ---------------- head2: out = sigmoid(g . HW2[ag] + Hb2[ag]) ----------------
    if (tid < BE) {
        float x = Hb2[ag];
        #pragma unroll
        for (int j = 0; j < 32; ++j)
            x += gpart[tid * 36 + j] * HW2[(ag << 5) + j];
        out[(size_t)(e0 + tid) * N_AGENTS + ag] = 1.f / (1.f + expf(-x));
    }
}

extern "C" void kernel_launch(void* const* d_in, const int* in_sizes, int n_in,
                              void* d_out, int out_size, void* d_ws, size_t ws_size,
                              hipStream_t stream) {
    const float* obs = (const float*)d_in[0];
    const float* W1  = (const float*)d_in[1];
    const float* b1  = (const float*)d_in[2];
    const float* W2  = (const float*)d_in[3];
    const float* b2  = (const float*)d_in[4];
    const float* HW1 = (const float*)d_in[5];
    const float* Hb1 = (const float*)d_in[6];
    const float* HW2 = (const float*)d_in[7];
    const float* Hb2 = (const float*)d_in[8];
    float* out = (float*)d_out;

    unsigned short* W1T  = (unsigned short*)d_ws;     // 131072 elems
    unsigned short* W2T  = W1T + 131072;              // 262144 elems
    unsigned short* HW1T = W2T + 262144;              // 1048576 elems

    prep_weights_kernel<<<5632, 256, 0, stream>>>(W1, W2, HW1, W1T, W2T, HW1T);

    dim3 grid(N_ENVS / BE, N_AGENTS);
    fused_mlp_kernel<<<grid, 512, 0, stream>>>(obs, b1, b2, Hb1, HW2, Hb2,
                                               W1T, W2T, HW1T, out);
}

// Round 4
// 505.692 us; speedup vs baseline: 1.7522x; 1.7522x over previous
//
#include <hip/hip_runtime.h>
#include <hip/hip_bf16.h>
#include <math.h>

#define N_ENVS   4096
#define N_AGENTS 64
#define OBS_DIM  256
#define HIDDEN   512
#define HEADK    32
#define BE       64   // envs per block

typedef __attribute__((ext_vector_type(8))) short bf16x8;
typedef __attribute__((ext_vector_type(8))) unsigned short u16x8;
typedef __attribute__((ext_vector_type(4))) float f32x4;

static __device__ __forceinline__ unsigned short f2bf(float x) {
    union { float f; unsigned int u; } v; v.f = x;
    unsigned int r = (v.u + 0x7FFFu + ((v.u >> 16) & 1u)) >> 16;
    return (unsigned short)r;
}

// Convert + transpose weights to bf16, N-major (so B-fragments are 16B contiguous).
__global__ void prep_weights_kernel(const float* __restrict__ W1,
                                    const float* __restrict__ W2,
                                    const float* __restrict__ HW1,
                                    unsigned short* __restrict__ W1T,
                                    unsigned short* __restrict__ W2T,
                                    unsigned short* __restrict__ HW1T) {
    int id = blockIdx.x * 256 + threadIdx.x;
    if (id < 131072) {                      // W1 [256][512] -> W1T [512][256]
        int k = id >> 9, n = id & 511;
        W1T[n * 256 + k] = f2bf(W1[id]);
    } else if (id < 131072 + 262144) {      // W2 [512][512] -> W2T [512][512]
        int t = id - 131072;
        int k = t >> 9, n = t & 511;
        W2T[n * 512 + k] = f2bf(W2[t]);
    } else if (id < 131072 + 262144 + 1048576) {  // HW1 [64][512][32] -> HW1T [64][32][512]
        int t = id - (131072 + 262144);
        int ag = t >> 14;
        int rem = t & 16383;
        int hh = rem >> 5, c = rem & 31;
        HW1T[((ag << 5) + c) * 512 + hh] = f2bf(HW1[t]);
    }
}

// Fused: obs -> (GEMM1 relu) -> (GEMM2 relu) -> per-agent head1 relu -> head2 sigmoid.
// Block = 64 envs x 1 agent. 512 threads = 8 waves.
// Wave partition: each wave owns ALL 64 rows x 64 cols (4x4 fragments) -> every
// weight fragment is fetched from L2 exactly ONCE per block (round-1 layout
// fetched each twice). Depth-2 register prefetch on B hides L2 latency under
// the 16-MFMA cluster. 1 block/CU, cap 256 regs (launch_bounds(512,2)):
// round-2/3 lesson -- cap 128 < demand (64 AGPR acc + ~100 VGPR) => spill.
__launch_bounds__(512, 2)
__global__ void fused_mlp_kernel(const float* __restrict__ obs,
                                 const float* __restrict__ b1,
                                 const float* __restrict__ b2,
                                 const float* __restrict__ Hb1,
                                 const float* __restrict__ HW2,
                                 const float* __restrict__ Hb2,
                                 const unsigned short* __restrict__ W1T,
                                 const unsigned short* __restrict__ W2T,
                                 const unsigned short* __restrict__ HW1T,
                                 float* __restrict__ out) {
    __shared__ unsigned short buf[BE * 512];    // 64 KB: obs tile, then h, then feat
    __shared__ float gpart[BE * 36];            // 9 KB : g partials (pad 36)

    const int tid  = threadIdx.x;
    const int lane = tid & 63;
    const int wid  = tid >> 6;   // 0..7 : col group (64 cols each)
    const int l15  = lane & 15;
    const int lk   = lane >> 4;  // 0..3
    const int e0   = blockIdx.x * BE;
    const int ag   = blockIdx.y;

    const f32x4 fzero = {0.f, 0.f, 0.f, 0.f};

    // ---------------- stage obs tile (fp32 -> bf16, swizzled, [64][256]) ----------------
    {
        const float* src = obs + (size_t)e0 * (N_AGENTS * OBS_DIM) + (size_t)ag * OBS_DIM;
        #pragma unroll
        for (int g = 0; g < 4; ++g) {
            int gi  = tid + 512 * g;            // 2048 groups of 8 elems
            int row = gi >> 5;                  // 32 groups per row
            int kg  = (gi & 31) << 3;
            const float4* p = reinterpret_cast<const float4*>(src + (size_t)row * (N_AGENTS * OBS_DIM) + kg);
            float4 v0 = p[0], v1 = p[1];
            u16x8 w;
            w[0] = f2bf(v0.x); w[1] = f2bf(v0.y); w[2] = f2bf(v0.z); w[3] = f2bf(v0.w);
            w[4] = f2bf(v1.x); w[5] = f2bf(v1.y); w[6] = f2bf(v1.z); w[7] = f2bf(v1.w);
            int byt = (row * 512 + kg * 2) ^ ((row & 7) << 4);
            *reinterpret_cast<u16x8*>(&buf[byt >> 1]) = w;
        }
    }
    __syncthreads();

    // ---------------- GEMM1: h = relu(obs @ W1 + b1), K=256 ----------------
    f32x4 acc[4][4];   // [mi rows][ni cols]
    #pragma unroll
    for (int i = 0; i < 4; ++i)
        #pragma unroll
        for (int j = 0; j < 4; ++j) acc[i][j] = fzero;

    {
        const unsigned short* bbase = W1T + (size_t)(wid * 64 + l15) * 256 + lk * 8;
        bf16x8 bcur[4], bnxt[4];
        #pragma unroll
        for (int ni = 0; ni < 4; ++ni)
            bcur[ni] = *reinterpret_cast<const bf16x8*>(bbase + ni * 16 * 256);
        #pragma unroll
        for (int ks = 0; ks < 8; ++ks) {
            const int kn = (ks < 7 ? ks + 1 : 7);
            #pragma unroll
            for (int ni = 0; ni < 4; ++ni)
                bnxt[ni] = *reinterpret_cast<const bf16x8*>(bbase + ni * 16 * 256 + kn * 32);
            const int kk = ks * 32 + lk * 8;
            bf16x8 af[4];
            #pragma unroll
            for (int mi = 0; mi < 4; ++mi) {
                int row = mi * 16 + l15;
                int byt = (row * 512 + kk * 2) ^ ((row & 7) << 4);
                af[mi] = *reinterpret_cast<const bf16x8*>(&buf[byt >> 1]);
            }
            #pragma unroll
            for (int ni = 0; ni < 4; ++ni)
                #pragma unroll
                for (int mi = 0; mi < 4; ++mi)
                    acc[mi][ni] = __builtin_amdgcn_mfma_f32_16x16x32_bf16(af[mi], bcur[ni], acc[mi][ni], 0, 0, 0);
            #pragma unroll
            for (int ni = 0; ni < 4; ++ni) bcur[ni] = bnxt[ni];
        }
    }
    __syncthreads();   // all obs reads done -> safe to overwrite buf with h

    // epilogue: +b1, relu, write h into buf ([64][512] swizzled)
    #pragma unroll
    for (int ni = 0; ni < 4; ++ni) {
        int col = wid * 64 + ni * 16 + l15;
        float bias = b1[col];
        #pragma unroll
        for (int mi = 0; mi < 4; ++mi)
            #pragma unroll
            for (int r = 0; r < 4; ++r) {
                int row = mi * 16 + lk * 4 + r;
                float v = acc[mi][ni][r] + bias;
                v = v > 0.f ? v : 0.f;
                int byt = (row * 1024 + col * 2) ^ ((row & 7) << 4);
                buf[byt >> 1] = f2bf(v);
            }
    }
    __syncthreads();

    // ---------------- GEMM2: feat = relu(h @ W2 + b2), K=512 ----------------
    #pragma unroll
    for (int i = 0; i < 4; ++i)
        #pragma unroll
        for (int j = 0; j < 4; ++j) acc[i][j] = fzero;

    {
        const unsigned short* bbase = W2T + (size_t)(wid * 64 + l15) * 512 + lk * 8;
        bf16x8 bcur[4], bnxt[4];
        #pragma unroll
        for (int ni = 0; ni < 4; ++ni)
            bcur[ni] = *reinterpret_cast<const bf16x8*>(bbase + ni * 16 * 512);
        #pragma unroll
        for (int ks = 0; ks < 16; ++ks) {
            const int kn = (ks < 15 ? ks + 1 : 15);
            #pragma unroll
            for (int ni = 0; ni < 4; ++ni)
                bnxt[ni] = *reinterpret_cast<const bf16x8*>(bbase + ni * 16 * 512 + kn * 32);
            const int kk = ks * 32 + lk * 8;
            bf16x8 af[4];
            #pragma unroll
            for (int mi = 0; mi < 4; ++mi) {
                int row = mi * 16 + l15;
                int byt = (row * 1024 + kk * 2) ^ ((row & 7) << 4);
                af[mi] = *reinterpret_cast<const bf16x8*>(&buf[byt >> 1]);
            }
            #pragma unroll
            for (int ni = 0; ni < 4; ++ni)
                #pragma unroll
                for (int mi = 0; mi < 4; ++mi)
                    acc[mi][ni] = __builtin_amdgcn_mfma_f32_16x16x32_bf16(af[mi], bcur[ni], acc[mi][ni], 0, 0, 0);
            #pragma unroll
            for (int ni = 0; ni < 4; ++ni) bcur[ni] = bnxt[ni];
        }
    }
    __syncthreads();   // all h reads done -> safe to overwrite buf with feat

    // epilogue: +b2, relu, write feat into buf ([64][512] swizzled)
    #pragma unroll
    for (int ni = 0; ni < 4; ++ni) {
        int col = wid * 64 + ni * 16 + l15;
        float bias = b2[col];
        #pragma unroll
        for (int mi = 0; mi < 4; ++mi)
            #pragma unroll
            for (int r = 0; r < 4; ++r) {
                int row = mi * 16 + lk * 4 + r;
                float v = acc[mi][ni][r] + bias;
                v = v > 0.f ? v : 0.f;
                int byt = (row * 1024 + col * 2) ^ ((row & 7) << 4);
                buf[byt >> 1] = f2bf(v);
            }
    }
    __syncthreads();

    // ---------------- head1: g = relu(feat @ HW1[ag] + Hb1[ag]), N=32 ----------------
    // All 8 waves: 4-way M (16 rows each) x 2-way K-split (256 each), LDS reduce.
    {
        const int hm = wid >> 1;    // 0..3
        const int hk = wid & 1;     // 0..1
        f32x4 hacc[2] = {fzero, fzero};
        const unsigned short* hbase = HW1T + (size_t)((ag << 5) + l15) * 512 + hk * 256;
        #pragma unroll 2
        for (int ks = 0; ks < 8; ++ks) {
            const int kk = hk * 256 + ks * 32 + lk * 8;
            int row = hm * 16 + l15;
            int byt = (row * 1024 + kk * 2) ^ ((row & 7) << 4);
            bf16x8 afh = *reinterpret_cast<const bf16x8*>(&buf[byt >> 1]);
            #pragma unroll
            for (int ni = 0; ni < 2; ++ni) {
                bf16x8 bfh = *reinterpret_cast<const bf16x8*>(hbase + ni * 16 * 512 + ks * 32 + lk * 8);
                hacc[ni] = __builtin_amdgcn_mfma_f32_16x16x32_bf16(afh, bfh, hacc[ni], 0, 0, 0);
            }
        }
        if (hk == 0) {
            #pragma unroll
            for (int ni = 0; ni < 2; ++ni) {
                int col = ni * 16 + l15;
                float hb = Hb1[(ag << 5) + col];
                #pragma unroll
                for (int r = 0; r < 4; ++r) {
                    int row = hm * 16 + lk * 4 + r;
                    gpart[row * 36 + col] = hacc[ni][r] + hb;
                }
            }
        }
        __syncthreads();
        if (hk == 1) {
            #pragma unroll
            for (int ni = 0; ni < 2; ++ni) {
                int col = ni * 16 + l15;
                #pragma unroll
                for (int r = 0; r < 4; ++r) {
                    int row = hm * 16 + lk * 4 + r;
                    float v = gpart[row * 36 + col] + hacc[ni][r];
                    gpart[row * 36 + col] = v > 0.f ? v : 0.f;
                }
            }
        }
        __syncthreads();
    }

    // ---------------- head2: out = sigmoid(g . HW2[ag] + Hb2[ag]) ----------------
    if (tid < BE) {
        float x = Hb2[ag];
        #pragma unroll
        for (int j = 0; j < 32; ++j)
            x += gpart[tid * 36 + j] * HW2[(ag << 5) + j];
        out[(size_t)(e0 + tid) * N_AGENTS + ag] = 1.f / (1.f + expf(-x));
    }
}

extern "C" void kernel_launch(void* const* d_in, const int* in_sizes, int n_in,
                              void* d_out, int out_size, void* d_ws, size_t ws_size,
                              hipStream_t stream) {
    const float* obs = (const float*)d_in[0];
    const float* W1  = (const float*)d_in[1];
    const float* b1  = (const float*)d_in[2];
    const float* W2  = (const float*)d_in[3];
    const float* b2  = (const float*)d_in[4];
    const float* HW1 = (const float*)d_in[5];
    const float* Hb1 = (const float*)d_in[6];
    const float* HW2 = (const float*)d_in[7];
    const float* Hb2 = (const float*)d_in[8];
    float* out = (float*)d_out;

    unsigned short* W1T  = (unsigned short*)d_ws;     // 131072 elems
    unsigned short* W2T  = W1T + 131072;              // 262144 elems
    unsigned short* HW1T = W2T + 262144;              // 1048576 elems

    prep_weights_kernel<<<5632, 256, 0, stream>>>(W1, W2, HW1, W1T, W2T, HW1T);

    dim3 grid(N_ENVS / BE, N_AGENTS);
    fused_mlp_kernel<<<grid, 512, 0, stream>>>(obs, b1, b2, Hb1, HW2, Hb2,
                                               W1T, W2T, HW1T, out);
}

// Round 5
// 469.476 us; speedup vs baseline: 1.8874x; 1.0771x over previous
//
#include <hip/hip_runtime.h>
#include <hip/hip_bf16.h>
#include <math.h>

#define N_ENVS   4096
#define N_AGENTS 64
#define OBS_DIM  256
#define HIDDEN   512
#define HEADK    32
#define BROWS    128   // rows per block = 64 envs x 2 agents

typedef __attribute__((ext_vector_type(8))) short bf16x8;
typedef __attribute__((ext_vector_type(8))) unsigned short u16x8;
typedef __attribute__((ext_vector_type(4))) float f32x4;

static __device__ __forceinline__ unsigned short f2bf(float x) {
    union { float f; unsigned int u; } v; v.f = x;
    unsigned int r = (v.u + 0x7FFFu + ((v.u >> 16) & 1u)) >> 16;
    return (unsigned short)r;
}

// Convert + transpose weights to bf16, N-major (so B-fragments are 16B contiguous).
__global__ void prep_weights_kernel(const float* __restrict__ W1,
                                    const float* __restrict__ W2,
                                    const float* __restrict__ HW1,
                                    unsigned short* __restrict__ W1T,
                                    unsigned short* __restrict__ W2T,
                                    unsigned short* __restrict__ HW1T) {
    int id = blockIdx.x * 256 + threadIdx.x;
    if (id < 131072) {                      // W1 [256][512] -> W1T [512][256]
        int k = id >> 9, n = id & 511;
        W1T[n * 256 + k] = f2bf(W1[id]);
    } else if (id < 131072 + 262144) {      // W2 [512][512] -> W2T [512][512]
        int t = id - 131072;
        int k = t >> 9, n = t & 511;
        W2T[n * 512 + k] = f2bf(W2[t]);
    } else if (id < 131072 + 262144 + 1048576) {  // HW1 [64][512][32] -> HW1T [64][32][512]
        int t = id - (131072 + 262144);
        int ag = t >> 14;
        int rem = t & 16383;
        int hh = rem >> 5, c = rem & 31;
        HW1T[((ag << 5) + c) * 512 + hh] = f2bf(HW1[t]);
    }
}

// Fused: obs -> (GEMM1 relu) -> (GEMM2 relu) -> per-agent head1 relu -> head2 sigmoid.
// Block = 64 envs x 2 AGENTS = 128 rows (shared MLP doesn't care which agent a
// row is; weights streamed once per block over 2x rows -> halves per-CU weight
// traffic AND halves per-env count of serial phases/barriers/stage latencies).
// 512 threads = 8 waves; each wave owns all 128 rows x 64 cols (8x4 frags,
// 128 acc regs). B register-double-buffered. Rows laid out j*64+e (j=agent in
// pair): head1 = 4 waves per agent, full K, no reduce barrier.
// Round-2/3 lesson: reg cap 128 spills with big acc -> keep launch_bounds(512,2)
// (cap 256, 1 block/CU); demand est: 128 acc + 32 af + 32 bdbuf + ~35 = 227.
__launch_bounds__(512, 2)
__global__ void fused_mlp_kernel(const float* __restrict__ obs,
                                 const float* __restrict__ b1,
                                 const float* __restrict__ b2,
                                 const float* __restrict__ Hb1,
                                 const float* __restrict__ HW2,
                                 const float* __restrict__ Hb2,
                                 const unsigned short* __restrict__ W1T,
                                 const unsigned short* __restrict__ W2T,
                                 const unsigned short* __restrict__ HW1T,
                                 float* __restrict__ out) {
    __shared__ unsigned short buf[BROWS * 512];  // 128 KB: obs(first half), h, feat
    __shared__ float gpart[BROWS * 36];          // 18 KB : g (pad 36)

    const int tid  = threadIdx.x;
    const int lane = tid & 63;
    const int wid  = tid >> 6;   // 0..7 : col group (64 cols each)
    const int l15  = lane & 15;
    const int lk   = lane >> 4;  // 0..3
    const int e0   = blockIdx.x * 64;
    const int ap   = blockIdx.y; // agent pair: agents 2ap, 2ap+1

    const f32x4 fzero = {0.f, 0.f, 0.f, 0.f};

    // ------------- stage obs tile [128][256] bf16 swizzled; row = j*64 + e -------------
    {
        #pragma unroll
        for (int g = 0; g < 8; ++g) {
            int gi  = tid + 512 * g;            // 4096 groups of 8 floats
            int row = gi >> 5;                  // 0..127
            int kg  = (gi & 31) << 3;
            int e   = row & 63, j = row >> 6;
            const float4* p = reinterpret_cast<const float4*>(
                obs + ((size_t)(e0 + e) * N_AGENTS + (2 * ap + j)) * OBS_DIM + kg);
            float4 v0 = p[0], v1 = p[1];
            u16x8 w;
            w[0] = f2bf(v0.x); w[1] = f2bf(v0.y); w[2] = f2bf(v0.z); w[3] = f2bf(v0.w);
            w[4] = f2bf(v1.x); w[5] = f2bf(v1.y); w[6] = f2bf(v1.z); w[7] = f2bf(v1.w);
            int byt = (row * 512 + kg * 2) ^ ((row & 7) << 4);
            *reinterpret_cast<u16x8*>(&buf[byt >> 1]) = w;
        }
    }
    __syncthreads();

    // ---------------- GEMM1: h = relu(obs @ W1 + b1), K=256 ----------------
    f32x4 acc[8][4];   // [mi rows 0..127][ni cols]
    #pragma unroll
    for (int i = 0; i < 8; ++i)
        #pragma unroll
        for (int j = 0; j < 4; ++j) acc[i][j] = fzero;

    {
        const unsigned short* bbase = W1T + (size_t)(wid * 64 + l15) * 256 + lk * 8;
        bf16x8 bcur[4], bnxt[4];
        #pragma unroll
        for (int ni = 0; ni < 4; ++ni)
            bcur[ni] = *reinterpret_cast<const bf16x8*>(bbase + ni * 16 * 256);
        #pragma unroll 2
        for (int ks = 0; ks < 8; ++ks) {
            const int kn = (ks < 7 ? ks + 1 : 7);
            #pragma unroll
            for (int ni = 0; ni < 4; ++ni)
                bnxt[ni] = *reinterpret_cast<const bf16x8*>(bbase + ni * 16 * 256 + kn * 32);
            const int kk = ks * 32 + lk * 8;
            bf16x8 af[8];
            #pragma unroll
            for (int mi = 0; mi < 8; ++mi) {
                int row = mi * 16 + l15;
                int byt = (row * 512 + kk * 2) ^ ((row & 7) << 4);
                af[mi] = *reinterpret_cast<const bf16x8*>(&buf[byt >> 1]);
            }
            #pragma unroll
            for (int ni = 0; ni < 4; ++ni)
                #pragma unroll
                for (int mi = 0; mi < 8; ++mi)
                    acc[mi][ni] = __builtin_amdgcn_mfma_f32_16x16x32_bf16(af[mi], bcur[ni], acc[mi][ni], 0, 0, 0);
            #pragma unroll
            for (int ni = 0; ni < 4; ++ni) bcur[ni] = bnxt[ni];
        }
    }
    __syncthreads();   // all obs reads done -> safe to overwrite buf with h

    // epilogue: +b1, relu, write h into buf ([128][512] swizzled)
    #pragma unroll
    for (int ni = 0; ni < 4; ++ni) {
        int col = wid * 64 + ni * 16 + l15;
        float bias = b1[col];
        #pragma unroll
        for (int mi = 0; mi < 8; ++mi)
            #pragma unroll
            for (int r = 0; r < 4; ++r) {
                int row = mi * 16 + lk * 4 + r;
                float v = acc[mi][ni][r] + bias;
                v = v > 0.f ? v : 0.f;
                int byt = (row * 1024 + col * 2) ^ ((row & 7) << 4);
                buf[byt >> 1] = f2bf(v);
            }
    }
    __syncthreads();

    // ---------------- GEMM2: feat = relu(h @ W2 + b2), K=512 ----------------
    #pragma unroll
    for (int i = 0; i < 8; ++i)
        #pragma unroll
        for (int j = 0; j < 4; ++j) acc[i][j] = fzero;

    {
        const unsigned short* bbase = W2T + (size_t)(wid * 64 + l15) * 512 + lk * 8;
        bf16x8 bcur[4], bnxt[4];
        #pragma unroll
        for (int ni = 0; ni < 4; ++ni)
            bcur[ni] = *reinterpret_cast<const bf16x8*>(bbase + ni * 16 * 512);
        #pragma unroll 2
        for (int ks = 0; ks < 16; ++ks) {
            const int kn = (ks < 15 ? ks + 1 : 15);
            #pragma unroll
            for (int ni = 0; ni < 4; ++ni)
                bnxt[ni] = *reinterpret_cast<const bf16x8*>(bbase + ni * 16 * 512 + kn * 32);
            const int kk = ks * 32 + lk * 8;
            bf16x8 af[8];
            #pragma unroll
            for (int mi = 0; mi < 8; ++mi) {
                int row = mi * 16 + l15;
                int byt = (row * 1024 + kk * 2) ^ ((row & 7) << 4);
                af[mi] = *reinterpret_cast<const bf16x8*>(&buf[byt >> 1]);
            }
            #pragma unroll
            for (int ni = 0; ni < 4; ++ni)
                #pragma unroll
                for (int mi = 0; mi < 8; ++mi)
                    acc[mi][ni] = __builtin_amdgcn_mfma_f32_16x16x32_bf16(af[mi], bcur[ni], acc[mi][ni], 0, 0, 0);
            #pragma unroll
            for (int ni = 0; ni < 4; ++ni) bcur[ni] = bnxt[ni];
        }
    }
    __syncthreads();   // all h reads done -> safe to overwrite buf with feat

    // epilogue: +b2, relu, write feat into buf ([128][512] swizzled)
    #pragma unroll
    for (int ni = 0; ni < 4; ++ni) {
        int col = wid * 64 + ni * 16 + l15;
        float bias = b2[col];
        #pragma unroll
        for (int mi = 0; mi < 8; ++mi)
            #pragma unroll
            for (int r = 0; r < 4; ++r) {
                int row = mi * 16 + lk * 4 + r;
                float v = acc[mi][ni][r] + bias;
                v = v > 0.f ? v : 0.f;
                int byt = (row * 1024 + col * 2) ^ ((row & 7) << 4);
                buf[byt >> 1] = f2bf(v);
            }
    }
    __syncthreads();

    // ---------------- head1: g = relu(feat @ HW1[agent] + Hb1), N=32 ----------------
    // 4 waves per agent of the pair, each wave: 16 rows x 32 cols, full K=512.
    {
        const int ja = wid >> 2;              // agent within pair
        const int hm = wid & 3;               // row quarter within that agent
        const int a32 = ((2 * ap + ja) << 5);
        f32x4 hacc[2] = {fzero, fzero};
        const unsigned short* hbase = HW1T + (size_t)(a32 + l15) * 512 + lk * 8;
        #pragma unroll 2
        for (int ks = 0; ks < 16; ++ks) {
            const int kk = ks * 32 + lk * 8;
            int row = ja * 64 + hm * 16 + l15;
            int byt = (row * 1024 + kk * 2) ^ ((row & 7) << 4);
            bf16x8 afh = *reinterpret_cast<const bf16x8*>(&buf[byt >> 1]);
            #pragma unroll
            for (int ni = 0; ni < 2; ++ni) {
                bf16x8 bfh = *reinterpret_cast<const bf16x8*>(hbase + ni * 16 * 512 + ks * 32);
                hacc[ni] = __builtin_amdgcn_mfma_f32_16x16x32_bf16(afh, bfh, hacc[ni], 0, 0, 0);
            }
        }
        #pragma unroll
        for (int ni = 0; ni < 2; ++ni) {
            int col = ni * 16 + l15;
            float hb = Hb1[a32 + col];
            #pragma unroll
            for (int r = 0; r < 4; ++r) {
                int row = ja * 64 + hm * 16 + lk * 4 + r;
                float v = hacc[ni][r] + hb;
                gpart[row * 36 + col] = v > 0.f ? v : 0.f;
            }
        }
    }
    __syncthreads();

    // ---------------- head2: out = sigmoid(g . HW2[agent] + Hb2) ----------------
    if (tid < BROWS) {
        int e = tid & 63, j = tid >> 6;
        int a = 2 * ap + j;
        float x = Hb2[a];
        #pragma unroll
        for (int k = 0; k < 32; ++k)
            x += gpart[tid * 36 + k] * HW2[(a << 5) + k];
        out[(size_t)(e0 + e) * N_AGENTS + a] = 1.f / (1.f + expf(-x));
    }
}

extern "C" void kernel_launch(void* const* d_in, const int* in_sizes, int n_in,
                              void* d_out, int out_size, void* d_ws, size_t ws_size,
                              hipStream_t stream) {
    const float* obs = (const float*)d_in[0];
    const float* W1  = (const float*)d_in[1];
    const float* b1  = (const float*)d_in[2];
    const float* W2  = (const float*)d_in[3];
    const float* b2  = (const float*)d_in[4];
    const float* HW1 = (const float*)d_in[5];
    const float* Hb1 = (const float*)d_in[6];
    const float* HW2 = (const float*)d_in[7];
    const float* Hb2 = (const float*)d_in[8];
    float* out = (float*)d_out;

    unsigned short* W1T  = (unsigned short*)d_ws;     // 131072 elems
    unsigned short* W2T  = W1T + 131072;              // 262144 elems
    unsigned short* HW1T = W2T + 262144;              // 1048576 elems

    prep_weights_kernel<<<5632, 256, 0, stream>>>(W1, W2, HW1, W1T, W2T, HW1T);

    dim3 grid(N_ENVS / 64, N_AGENTS / 2);
    fused_mlp_kernel<<<grid, 512, 0, stream>>>(obs, b1, b2, Hb1, HW2, Hb2,
                                               W1T, W2T, HW1T, out);
}

// Round 6
// 428.460 us; speedup vs baseline: 2.0681x; 1.0957x over previous
//
#include <hip/hip_runtime.h>
#include <hip/hip_bf16.h>
#include <math.h>

#define N_ENVS   4096
#define N_AGENTS 64
#define OBS_DIM  256
#define HIDDEN   512
#define HEADK    32
#define BROWS    128   // rows per block = 64 envs x 2 agents

typedef __attribute__((ext_vector_type(8))) short bf16x8;
typedef __attribute__((ext_vector_type(8))) unsigned short u16x8;
typedef __attribute__((ext_vector_type(4))) float f32x4;

static __device__ __forceinline__ unsigned short f2bf(float x) {
    union { float f; unsigned int u; } v; v.f = x;
    unsigned int r = (v.u + 0x7FFFu + ((v.u >> 16) & 1u)) >> 16;
    return (unsigned short)r;
}

// Convert + transpose weights to bf16, N-major (so B-fragments are 16B contiguous).
__global__ void prep_weights_kernel(const float* __restrict__ W1,
                                    const float* __restrict__ W2,
                                    const float* __restrict__ HW1,
                                    unsigned short* __restrict__ W1T,
                                    unsigned short* __restrict__ W2T,
                                    unsigned short* __restrict__ HW1T) {
    int id = blockIdx.x * 256 + threadIdx.x;
    if (id < 131072) {                      // W1 [256][512] -> W1T [512][256]
        int k = id >> 9, n = id & 511;
        W1T[n * 256 + k] = f2bf(W1[id]);
    } else if (id < 131072 + 262144) {      // W2 [512][512] -> W2T [512][512]
        int t = id - 131072;
        int k = t >> 9, n = t & 511;
        W2T[n * 512 + k] = f2bf(W2[t]);
    } else if (id < 131072 + 262144 + 1048576) {  // HW1 [64][512][32] -> HW1T [64][32][512]
        int t = id - (131072 + 262144);
        int ag = t >> 14;
        int rem = t & 16383;
        int hh = rem >> 5, c = rem & 31;
        HW1T[((ag << 5) + c) * 512 + hh] = f2bf(HW1[t]);
    }
}

// Fused: obs -> (GEMM1 relu) -> (GEMM2 relu) -> per-agent head1 relu -> head2 sigmoid.
// Block = 64 envs x 2 agents = 128 rows. 512 threads = 8 waves; each wave owns
// all 128 rows x 64 cols (8x4 frags, 128 acc regs).
// Register-pressure engineering (round-5 lesson: unroll-2 + af[8] cluster
// spilled 197MB at VGPR cap 256):
//   - K-loops are `#pragma unroll 1` (no cross-iteration live-range growth)
//   - A-fragments loaded in PAIRS interleaved with their MFMAs (peak 4 af regs)
//   - B depth-1 prefetch (bcur/bnxt = 32 regs)
//   - each phase's first B-fragments issued BEFORE the preceding barrier so
//     their L2 latency drains under the barrier.
// Peak est: 128 acc + 32 B + 4 af + ~25 addr ~= 190 < 256.
__launch_bounds__(512, 2)
__global__ void fused_mlp_kernel(const float* __restrict__ obs,
                                 const float* __restrict__ b1,
                                 const float* __restrict__ b2,
                                 const float* __restrict__ Hb1,
                                 const float* __restrict__ HW2,
                                 const float* __restrict__ Hb2,
                                 const unsigned short* __restrict__ W1T,
                                 const unsigned short* __restrict__ W2T,
                                 const unsigned short* __restrict__ HW1T,
                                 float* __restrict__ out) {
    __shared__ unsigned short buf[BROWS * 512];  // 128 KB: obs(first half), h, feat
    __shared__ float gpart[BROWS * 36];          // 18 KB : g (pad 36)

    const int tid  = threadIdx.x;
    const int lane = tid & 63;
    const int wid  = tid >> 6;   // 0..7 : col group (64 cols each)
    const int l15  = lane & 15;
    const int lk   = lane >> 4;  // 0..3
    const int e0   = blockIdx.x * 64;
    const int ap   = blockIdx.y; // agent pair: agents 2ap, 2ap+1

    const f32x4 fzero = {0.f, 0.f, 0.f, 0.f};

    const unsigned short* bbase1 = W1T + (size_t)(wid * 64 + l15) * 256 + lk * 8;
    const unsigned short* bbase2 = W2T + (size_t)(wid * 64 + l15) * 512 + lk * 8;

    // GEMM1's first B-fragments: issue before staging so L2 latency hides
    // under the stage + barrier.
    bf16x8 bcur[4];
    #pragma unroll
    for (int ni = 0; ni < 4; ++ni)
        bcur[ni] = *reinterpret_cast<const bf16x8*>(bbase1 + ni * 16 * 256);

    // ------------- stage obs tile [128][256] bf16 swizzled; row = j*64 + e -------------
    {
        #pragma unroll
        for (int g = 0; g < 8; ++g) {
            int gi  = tid + 512 * g;            // 4096 groups of 8 floats
            int row = gi >> 5;                  // 0..127
            int kg  = (gi & 31) << 3;
            int e   = row & 63, j = row >> 6;
            const float4* p = reinterpret_cast<const float4*>(
                obs + ((size_t)(e0 + e) * N_AGENTS + (2 * ap + j)) * OBS_DIM + kg);
            float4 v0 = p[0], v1 = p[1];
            u16x8 w;
            w[0] = f2bf(v0.x); w[1] = f2bf(v0.y); w[2] = f2bf(v0.z); w[3] = f2bf(v0.w);
            w[4] = f2bf(v1.x); w[5] = f2bf(v1.y); w[6] = f2bf(v1.z); w[7] = f2bf(v1.w);
            int byt = (row * 512 + kg * 2) ^ ((row & 7) << 4);
            *reinterpret_cast<u16x8*>(&buf[byt >> 1]) = w;
        }
    }
    __syncthreads();

    // ---------------- GEMM1: h = relu(obs @ W1 + b1), K=256 ----------------
    f32x4 acc[8][4];   // [mi rows 0..127][ni cols]
    #pragma unroll
    for (int i = 0; i < 8; ++i)
        #pragma unroll
        for (int j = 0; j < 4; ++j) acc[i][j] = fzero;

    #pragma unroll 1
    for (int ks = 0; ks < 8; ++ks) {
        bf16x8 bnxt[4];
        const int kn = (ks < 7 ? ks + 1 : 7);
        #pragma unroll
        for (int ni = 0; ni < 4; ++ni)
            bnxt[ni] = *reinterpret_cast<const bf16x8*>(bbase1 + ni * 16 * 256 + kn * 32);
        const int kk = ks * 32 + lk * 8;
        #pragma unroll
        for (int mi = 0; mi < 8; mi += 2) {
            int r0 = mi * 16 + l15, r1 = r0 + 16;
            bf16x8 a0 = *reinterpret_cast<const bf16x8*>(&buf[((r0 * 512 + kk * 2) ^ ((r0 & 7) << 4)) >> 1]);
            bf16x8 a1 = *reinterpret_cast<const bf16x8*>(&buf[((r1 * 512 + kk * 2) ^ ((r1 & 7) << 4)) >> 1]);
            #pragma unroll
            for (int ni = 0; ni < 4; ++ni) {
                acc[mi][ni]     = __builtin_amdgcn_mfma_f32_16x16x32_bf16(a0, bcur[ni], acc[mi][ni], 0, 0, 0);
                acc[mi + 1][ni] = __builtin_amdgcn_mfma_f32_16x16x32_bf16(a1, bcur[ni], acc[mi + 1][ni], 0, 0, 0);
            }
        }
        #pragma unroll
        for (int ni = 0; ni < 4; ++ni) bcur[ni] = bnxt[ni];
    }

    // GEMM2's first B-fragments: issue before the epilogue barriers.
    #pragma unroll
    for (int ni = 0; ni < 4; ++ni)
        bcur[ni] = *reinterpret_cast<const bf16x8*>(bbase2 + ni * 16 * 512);

    __syncthreads();   // all obs reads done -> safe to overwrite buf with h

    // epilogue: +b1, relu, write h into buf ([128][512] swizzled)
    #pragma unroll
    for (int ni = 0; ni < 4; ++ni) {
        int col = wid * 64 + ni * 16 + l15;
        float bias = b1[col];
        #pragma unroll
        for (int mi = 0; mi < 8; ++mi)
            #pragma unroll
            for (int r = 0; r < 4; ++r) {
                int row = mi * 16 + lk * 4 + r;
                float v = acc[mi][ni][r] + bias;
                v = v > 0.f ? v : 0.f;
                int byt = (row * 1024 + col * 2) ^ ((row & 7) << 4);
                buf[byt >> 1] = f2bf(v);
            }
    }
    __syncthreads();

    // ---------------- GEMM2: feat = relu(h @ W2 + b2), K=512 ----------------
    #pragma unroll
    for (int i = 0; i < 8; ++i)
        #pragma unroll
        for (int j = 0; j < 4; ++j) acc[i][j] = fzero;

    #pragma unroll 1
    for (int ks = 0; ks < 16; ++ks) {
        bf16x8 bnxt[4];
        const int kn = (ks < 15 ? ks + 1 : 15);
        #pragma unroll
        for (int ni = 0; ni < 4; ++ni)
            bnxt[ni] = *reinterpret_cast<const bf16x8*>(bbase2 + ni * 16 * 512 + kn * 32);
        const int kk = ks * 32 + lk * 8;
        #pragma unroll
        for (int mi = 0; mi < 8; mi += 2) {
            int r0 = mi * 16 + l15, r1 = r0 + 16;
            bf16x8 a0 = *reinterpret_cast<const bf16x8*>(&buf[((r0 * 1024 + kk * 2) ^ ((r0 & 7) << 4)) >> 1]);
            bf16x8 a1 = *reinterpret_cast<const bf16x8*>(&buf[((r1 * 1024 + kk * 2) ^ ((r1 & 7) << 4)) >> 1]);
            #pragma unroll
            for (int ni = 0; ni < 4; ++ni) {
                acc[mi][ni]     = __builtin_amdgcn_mfma_f32_16x16x32_bf16(a0, bcur[ni], acc[mi][ni], 0, 0, 0);
                acc[mi + 1][ni] = __builtin_amdgcn_mfma_f32_16x16x32_bf16(a1, bcur[ni], acc[mi + 1][ni], 0, 0, 0);
            }
        }
        #pragma unroll
        for (int ni = 0; ni < 4; ++ni) bcur[ni] = bnxt[ni];
    }

    // head1's first B-fragments: issue before the epilogue barriers.
    const int ja  = wid >> 2;              // agent within pair
    const int hm  = wid & 3;               // row quarter within that agent
    const int a32 = ((2 * ap + ja) << 5);
    const unsigned short* hbase = HW1T + (size_t)(a32 + l15) * 512 + lk * 8;
    bf16x8 hb0 = *reinterpret_cast<const bf16x8*>(hbase);
    bf16x8 hb1v = *reinterpret_cast<const bf16x8*>(hbase + 16 * 512);

    __syncthreads();   // all h reads done -> safe to overwrite buf with feat

    // epilogue: +b2, relu, write feat into buf ([128][512] swizzled)
    #pragma unroll
    for (int ni = 0; ni < 4; ++ni) {
        int col = wid * 64 + ni * 16 + l15;
        float bias = b2[col];
        #pragma unroll
        for (int mi = 0; mi < 8; ++mi)
            #pragma unroll
            for (int r = 0; r < 4; ++r) {
                int row = mi * 16 + lk * 4 + r;
                float v = acc[mi][ni][r] + bias;
                v = v > 0.f ? v : 0.f;
                int byt = (row * 1024 + col * 2) ^ ((row & 7) << 4);
                buf[byt >> 1] = f2bf(v);
            }
    }
    __syncthreads();

    // ---------------- head1: g = relu(feat @ HW1[agent] + Hb1), N=32 ----------------
    // 4 waves per agent of the pair, each wave: 16 rows x 32 cols, full K=512.
    {
        f32x4 hacc[2] = {fzero, fzero};
        #pragma unroll 1
        for (int ks = 0; ks < 16; ++ks) {
            const int kn = (ks < 15 ? ks + 1 : 15);
            bf16x8 hn0 = *reinterpret_cast<const bf16x8*>(hbase + kn * 32);
            bf16x8 hn1 = *reinterpret_cast<const bf16x8*>(hbase + 16 * 512 + kn * 32);
            const int kk = ks * 32 + lk * 8;
            int row = ja * 64 + hm * 16 + l15;
            int byt = (row * 1024 + kk * 2) ^ ((row & 7) << 4);
            bf16x8 afh = *reinterpret_cast<const bf16x8*>(&buf[byt >> 1]);
            hacc[0] = __builtin_amdgcn_mfma_f32_16x16x32_bf16(afh, hb0, hacc[0], 0, 0, 0);
            hacc[1] = __builtin_amdgcn_mfma_f32_16x16x32_bf16(afh, hb1v, hacc[1], 0, 0, 0);
            hb0 = hn0; hb1v = hn1;
        }
        #pragma unroll
        for (int ni = 0; ni < 2; ++ni) {
            int col = ni * 16 + l15;
            float hb = Hb1[a32 + col];
            #pragma unroll
            for (int r = 0; r < 4; ++r) {
                int row = ja * 64 + hm * 16 + lk * 4 + r;
                float v = hacc[ni][r] + hb;
                gpart[row * 36 + col] = v > 0.f ? v : 0.f;
            }
        }
    }
    __syncthreads();

    // ---------------- head2: out = sigmoid(g . HW2[agent] + Hb2) ----------------
    if (tid < BROWS) {
        int e = tid & 63, j = tid >> 6;
        int a = 2 * ap + j;
        float x = Hb2[a];
        #pragma unroll
        for (int k = 0; k < 32; ++k)
            x += gpart[tid * 36 + k] * HW2[(a << 5) + k];
        out[(size_t)(e0 + e) * N_AGENTS + a] = 1.f / (1.f + expf(-x));
    }
}

extern "C" void kernel_launch(void* const* d_in, const int* in_sizes, int n_in,
                              void* d_out, int out_size, void* d_ws, size_t ws_size,
                              hipStream_t stream) {
    const float* obs = (const float*)d_in[0];
    const float* W1  = (const float*)d_in[1];
    const float* b1  = (const float*)d_in[2];
    const float* W2  = (const float*)d_in[3];
    const float* b2  = (const float*)d_in[4];
    const float* HW1 = (const float*)d_in[5];
    const float* Hb1 = (const float*)d_in[6];
    const float* HW2 = (const float*)d_in[7];
    const float* Hb2 = (const float*)d_in[8];
    float* out = (float*)d_out;

    unsigned short* W1T  = (unsigned short*)d_ws;     // 131072 elems
    unsigned short* W2T  = W1T + 131072;              // 262144 elems
    unsigned short* HW1T = W2T + 262144;              // 1048576 elems

    prep_weights_kernel<<<5632, 256, 0, stream>>>(W1, W2, HW1, W1T, W2T, HW1T);

    dim3 grid(N_ENVS / 64, N_AGENTS / 2);
    fused_mlp_kernel<<<grid, 512, 0, stream>>>(obs, b1, b2, Hb1, HW2, Hb2,
                                               W1T, W2T, HW1T, out);
}

// Round 7
// 409.271 us; speedup vs baseline: 2.1650x; 1.0469x over previous
//
#include <hip/hip_runtime.h>
#include <hip/hip_bf16.h>
#include <math.h>

#define N_ENVS   4096
#define N_AGENTS 64
#define OBS_DIM  256
#define HIDDEN   512
#define HEADK    32
#define BROWS    128   // rows per block = 64 envs x 2 agents

typedef __attribute__((ext_vector_type(8))) short bf16x8;
typedef __attribute__((ext_vector_type(8))) unsigned short u16x8;
typedef __attribute__((ext_vector_type(4))) float f32x4;

static __device__ __forceinline__ unsigned short f2bf(float x) {
    union { float f; unsigned int u; } v; v.f = x;
    unsigned int r = (v.u + 0x7FFFu + ((v.u >> 16) & 1u)) >> 16;
    return (unsigned short)r;
}

// Convert + transpose weights to bf16, N-major (so B-fragments are 16B contiguous).
__global__ void prep_weights_kernel(const float* __restrict__ W1,
                                    const float* __restrict__ W2,
                                    const float* __restrict__ HW1,
                                    unsigned short* __restrict__ W1T,
                                    unsigned short* __restrict__ W2T,
                                    unsigned short* __restrict__ HW1T) {
    int id = blockIdx.x * 256 + threadIdx.x;
    if (id < 131072) {                      // W1 [256][512] -> W1T [512][256]
        int k = id >> 9, n = id & 511;
        W1T[n * 256 + k] = f2bf(W1[id]);
    } else if (id < 131072 + 262144) {      // W2 [512][512] -> W2T [512][512]
        int t = id - 131072;
        int k = t >> 9, n = t & 511;
        W2T[n * 512 + k] = f2bf(W2[t]);
    } else if (id < 131072 + 262144 + 1048576) {  // HW1 [64][512][32] -> HW1T [64][32][512]
        int t = id - (131072 + 262144);
        int ag = t >> 14;
        int rem = t & 16383;
        int hh = rem >> 5, c = rem & 31;
        HW1T[((ag << 5) + c) * 512 + hh] = f2bf(HW1[t]);
    }
}

// Fused: obs -> (GEMM1 relu) -> (GEMM2 relu) -> per-agent head1 relu -> head2 sigmoid.
// Block = 64 envs x 2 agents = 128 rows. 1024 threads = 16 waves; each wave
// owns all 128 rows x 32 COLS -> acc[8][2] = 64 regs only.
// Round-5/6 lesson: acc=128 leaves only 128 arch regs at cap 256 -> chronic
// spill (161-197MB scratch). Halving acc/wave and doubling waves/SIMD (4) both
// kills the spill (demand ~113 < cap 128 from launch_bounds(1024)) and doubles
// latency-hiding TLP. Weights still fetched exactly once per block.
__launch_bounds__(1024, 1)
__global__ void fused_mlp_kernel(const float* __restrict__ obs,
                                 const float* __restrict__ b1,
                                 const float* __restrict__ b2,
                                 const float* __restrict__ Hb1,
                                 const float* __restrict__ HW2,
                                 const float* __restrict__ Hb2,
                                 const unsigned short* __restrict__ W1T,
                                 const unsigned short* __restrict__ W2T,
                                 const unsigned short* __restrict__ HW1T,
                                 float* __restrict__ out) {
    __shared__ unsigned short buf[BROWS * 512];  // 128 KB: obs(first half), h, feat
    __shared__ float gpart[BROWS * 36];          // 18 KB : g (pad 36)

    const int tid  = threadIdx.x;
    const int lane = tid & 63;
    const int wid  = tid >> 6;   // 0..15 : col group (32 cols each)
    const int l15  = lane & 15;
    const int lk   = lane >> 4;  // 0..3
    const int e0   = blockIdx.x * 64;
    const int ap   = blockIdx.y; // agent pair: agents 2ap, 2ap+1

    const f32x4 fzero = {0.f, 0.f, 0.f, 0.f};

    // ------------- stage obs tile [128][256] bf16 swizzled; row = j*64 + e -------------
    {
        #pragma unroll
        for (int g = 0; g < 4; ++g) {
            int gi  = tid + 1024 * g;           // 4096 groups of 8 floats
            int row = gi >> 5;                  // 0..127
            int kg  = (gi & 31) << 3;
            int e   = row & 63, j = row >> 6;
            const float4* p = reinterpret_cast<const float4*>(
                obs + ((size_t)(e0 + e) * N_AGENTS + (2 * ap + j)) * OBS_DIM + kg);
            float4 v0 = p[0], v1 = p[1];
            u16x8 w;
            w[0] = f2bf(v0.x); w[1] = f2bf(v0.y); w[2] = f2bf(v0.z); w[3] = f2bf(v0.w);
            w[4] = f2bf(v1.x); w[5] = f2bf(v1.y); w[6] = f2bf(v1.z); w[7] = f2bf(v1.w);
            int byt = (row * 512 + kg * 2) ^ ((row & 7) << 4);
            *reinterpret_cast<u16x8*>(&buf[byt >> 1]) = w;
        }
    }
    __syncthreads();

    // ---------------- GEMM1: h = relu(obs @ W1 + b1), K=256 ----------------
    f32x4 acc[8][2];   // [mi rows 0..127][ni cols]
    #pragma unroll
    for (int i = 0; i < 8; ++i)
        #pragma unroll
        for (int j = 0; j < 2; ++j) acc[i][j] = fzero;

    {
        const unsigned short* bbase = W1T + (size_t)(wid * 32 + l15) * 256 + lk * 8;
        bf16x8 bcur[2];
        #pragma unroll
        for (int ni = 0; ni < 2; ++ni)
            bcur[ni] = *reinterpret_cast<const bf16x8*>(bbase + ni * 16 * 256);
        #pragma unroll 1
        for (int ks = 0; ks < 8; ++ks) {
            bf16x8 bnxt[2];
            const int kn = (ks < 7 ? ks + 1 : 7);
            #pragma unroll
            for (int ni = 0; ni < 2; ++ni)
                bnxt[ni] = *reinterpret_cast<const bf16x8*>(bbase + ni * 16 * 256 + kn * 32);
            const int kk = ks * 32 + lk * 8;
            #pragma unroll
            for (int mi = 0; mi < 8; mi += 2) {
                int r0 = mi * 16 + l15, r1 = r0 + 16;
                bf16x8 a0 = *reinterpret_cast<const bf16x8*>(&buf[((r0 * 512 + kk * 2) ^ ((r0 & 7) << 4)) >> 1]);
                bf16x8 a1 = *reinterpret_cast<const bf16x8*>(&buf[((r1 * 512 + kk * 2) ^ ((r1 & 7) << 4)) >> 1]);
                #pragma unroll
                for (int ni = 0; ni < 2; ++ni) {
                    acc[mi][ni]     = __builtin_amdgcn_mfma_f32_16x16x32_bf16(a0, bcur[ni], acc[mi][ni], 0, 0, 0);
                    acc[mi + 1][ni] = __builtin_amdgcn_mfma_f32_16x16x32_bf16(a1, bcur[ni], acc[mi + 1][ni], 0, 0, 0);
                }
            }
            bcur[0] = bnxt[0]; bcur[1] = bnxt[1];
        }
    }
    __syncthreads();   // all obs reads done -> safe to overwrite buf with h

    // epilogue: +b1, relu, write h into buf ([128][512] swizzled)
    #pragma unroll
    for (int ni = 0; ni < 2; ++ni) {
        int col = wid * 32 + ni * 16 + l15;
        float bias = b1[col];
        #pragma unroll
        for (int mi = 0; mi < 8; ++mi)
            #pragma unroll
            for (int r = 0; r < 4; ++r) {
                int row = mi * 16 + lk * 4 + r;
                float v = acc[mi][ni][r] + bias;
                v = v > 0.f ? v : 0.f;
                int byt = (row * 1024 + col * 2) ^ ((row & 7) << 4);
                buf[byt >> 1] = f2bf(v);
            }
    }
    __syncthreads();

    // ---------------- GEMM2: feat = relu(h @ W2 + b2), K=512 ----------------
    #pragma unroll
    for (int i = 0; i < 8; ++i)
        #pragma unroll
        for (int j = 0; j < 2; ++j) acc[i][j] = fzero;

    {
        const unsigned short* bbase = W2T + (size_t)(wid * 32 + l15) * 512 + lk * 8;
        bf16x8 bcur[2];
        #pragma unroll
        for (int ni = 0; ni < 2; ++ni)
            bcur[ni] = *reinterpret_cast<const bf16x8*>(bbase + ni * 16 * 512);
        #pragma unroll 1
        for (int ks = 0; ks < 16; ++ks) {
            bf16x8 bnxt[2];
            const int kn = (ks < 15 ? ks + 1 : 15);
            #pragma unroll
            for (int ni = 0; ni < 2; ++ni)
                bnxt[ni] = *reinterpret_cast<const bf16x8*>(bbase + ni * 16 * 512 + kn * 32);
            const int kk = ks * 32 + lk * 8;
            #pragma unroll
            for (int mi = 0; mi < 8; mi += 2) {
                int r0 = mi * 16 + l15, r1 = r0 + 16;
                bf16x8 a0 = *reinterpret_cast<const bf16x8*>(&buf[((r0 * 1024 + kk * 2) ^ ((r0 & 7) << 4)) >> 1]);
                bf16x8 a1 = *reinterpret_cast<const bf16x8*>(&buf[((r1 * 1024 + kk * 2) ^ ((r1 & 7) << 4)) >> 1]);
                #pragma unroll
                for (int ni = 0; ni < 2; ++ni) {
                    acc[mi][ni]     = __builtin_amdgcn_mfma_f32_16x16x32_bf16(a0, bcur[ni], acc[mi][ni], 0, 0, 0);
                    acc[mi + 1][ni] = __builtin_amdgcn_mfma_f32_16x16x32_bf16(a1, bcur[ni], acc[mi + 1][ni], 0, 0, 0);
                }
            }
            bcur[0] = bnxt[0]; bcur[1] = bnxt[1];
        }
    }
    __syncthreads();   // all h reads done -> safe to overwrite buf with feat

    // epilogue: +b2, relu, write feat into buf ([128][512] swizzled)
    #pragma unroll
    for (int ni = 0; ni < 2; ++ni) {
        int col = wid * 32 + ni * 16 + l15;
        float bias = b2[col];
        #pragma unroll
        for (int mi = 0; mi < 8; ++mi)
            #pragma unroll
            for (int r = 0; r < 4; ++r) {
                int row = mi * 16 + lk * 4 + r;
                float v = acc[mi][ni][r] + bias;
                v = v > 0.f ? v : 0.f;
                int byt = (row * 1024 + col * 2) ^ ((row & 7) << 4);
                buf[byt >> 1] = f2bf(v);
            }
    }
    __syncthreads();

    // ---------------- head1: g = relu(feat @ HW1[agent] + Hb1), N=32 ----------------
    // 16 waves: per agent of the pair, 4 row-quarters x 2 col-halves, full K=512.
    {
        const int ja  = wid >> 3;             // agent within pair
        const int sub = wid & 7;
        const int hm  = sub >> 1;             // row quarter 0..3
        const int hc  = sub & 1;              // col half 0..1
        const int a32 = ((2 * ap + ja) << 5);
        const unsigned short* hbase = HW1T + (size_t)(a32 + hc * 16 + l15) * 512 + lk * 8;
        f32x4 hacc = fzero;
        bf16x8 hb = *reinterpret_cast<const bf16x8*>(hbase);
        #pragma unroll 1
        for (int ks = 0; ks < 16; ++ks) {
            const int kn = (ks < 15 ? ks + 1 : 15);
            bf16x8 hn = *reinterpret_cast<const bf16x8*>(hbase + kn * 32);
            const int kk = ks * 32 + lk * 8;
            int row = ja * 64 + hm * 16 + l15;
            int byt = (row * 1024 + kk * 2) ^ ((row & 7) << 4);
            bf16x8 afh = *reinterpret_cast<const bf16x8*>(&buf[byt >> 1]);
            hacc = __builtin_amdgcn_mfma_f32_16x16x32_bf16(afh, hb, hacc, 0, 0, 0);
            hb = hn;
        }
        int col = hc * 16 + l15;
        float hbias = Hb1[a32 + col];
        #pragma unroll
        for (int r = 0; r < 4; ++r) {
            int row = ja * 64 + hm * 16 + lk * 4 + r;
            float v = hacc[r] + hbias;
            gpart[row * 36 + col] = v > 0.f ? v : 0.f;
        }
    }
    __syncthreads();

    // ---------------- head2: out = sigmoid(g . HW2[agent] + Hb2) ----------------
    if (tid < BROWS) {
        int e = tid & 63, j = tid >> 6;
        int a = 2 * ap + j;
        float x = Hb2[a];
        #pragma unroll
        for (int k = 0; k < 32; ++k)
            x += gpart[tid * 36 + k] * HW2[(a << 5) + k];
        out[(size_t)(e0 + e) * N_AGENTS + a] = 1.f / (1.f + expf(-x));
    }
}

extern "C" void kernel_launch(void* const* d_in, const int* in_sizes, int n_in,
                              void* d_out, int out_size, void* d_ws, size_t ws_size,
                              hipStream_t stream) {
    const float* obs = (const float*)d_in[0];
    const float* W1  = (const float*)d_in[1];
    const float* b1  = (const float*)d_in[2];
    const float* W2  = (const float*)d_in[3];
    const float* b2  = (const float*)d_in[4];
    const float* HW1 = (const float*)d_in[5];
    const float* Hb1 = (const float*)d_in[6];
    const float* HW2 = (const float*)d_in[7];
    const float* Hb2 = (const float*)d_in[8];
    float* out = (float*)d_out;

    unsigned short* W1T  = (unsigned short*)d_ws;     // 131072 elems
    unsigned short* W2T  = W1T + 131072;              // 262144 elems
    unsigned short* HW1T = W2T + 262144;              // 1048576 elems

    prep_weights_kernel<<<5632, 256, 0, stream>>>(W1, W2, HW1, W1T, W2T, HW1T);

    dim3 grid(N_ENVS / 64, N_AGENTS / 2);
    fused_mlp_kernel<<<grid, 1024, 0, stream>>>(obs, b1, b2, Hb1, HW2, Hb2,
                                                W1T, W2T, HW1T, out);
}